// Round 3
// baseline (108.308 us; speedup 1.0000x reference)
//
#include <hip/hip_runtime.h>
#include <hip/hip_bf16.h>

// out[b,h,i,j] = sum_d q[b,i,h,d] * T[128 + x[b,j] - x[b,i], h*64+d]
// Round 8: MEASUREMENT round. Rounds 6/7 (direct-global B-frags, 2x TLP)
// both regressed -> revert to the round-5 structure (best, 67.8us) and wrap
// the body in REPS=10. Purpose:
//  (1) K = (dur_us - 67.8)/9 isolates the kernel time from the ~45-48us of
//      harness poison-fill dispatches that dominate dur_us.
//  (2) at 10K > 43us the kernel finally OUTRANKS the fills in the top-5
//      table and we get its MfmaUtil/VALUBusy/LDS/occupancy counters.
// Loop is idempotent (same values rewritten) and race-free (2 barriers per
// rep cover stage->mfma->gather hazards; trailing barrier guards xi_s/Tl
// rewrite). asm memory clobber per rep defeats cross-rep CSE/DCE.
// NEXT ROUND: dur_us is NOT comparable to previous rounds. Set REPS back
// to 1 (or remove the loop) for any real candidate.

#define S_LEN 512
#define NH 8
#define HD 64
#define EDIM 512
#define TI 16      // i-rows per block; grid = B*NH*(S/TI) = 512 -> 2 blocks/CU
#define NR 256
#define TIP 18     // Ts row pad (floats): 72B rows, 8B-aligned, odd/16 bank spread
#define REPS 10

typedef __attribute__((ext_vector_type(8))) short bf16x8;
typedef __attribute__((ext_vector_type(4))) float f32x4;

__device__ __forceinline__ ushort2 pk_bf16(float a, float b) {
    union { __hip_bfloat162 h; ushort2 u; } v;
    v.h = __float22bfloat162_rn(float2{a, b});
    return v.u;
}

__global__ __launch_bounds__(256) void relpos_kernel(
    const float* __restrict__ q,     // [B, S, H, D]
    const float* __restrict__ et,    // [257, E]
    const int*   __restrict__ x,     // [B, S]
    const int*   __restrict__ maxx_p,
    float*       __restrict__ out)   // [B, H, S, S]
{
    const int tid = threadIdx.x;
    const int per = S_LEN / TI;                  // 32
    const int b   = blockIdx.x / (NH * per);
    const int h   = (blockIdx.x / per) % NH;
    const int i0  = (blockIdx.x % per) * TI;

    __shared__ unsigned short Tl[NR * HD];       // 32 KB swizzled bf16 table slice
    __shared__ float          Ts[NR][TIP];       // 18 KB scores, [r][i] layout
    __shared__ int            xi_s[TI];

    const int w    = tid >> 6;
    const int l    = tid & 63;
    const int quad = l >> 4;
    const int c    = l & 15;
    const int rrow = tid >> 4;                   // staging: row within iter group
    const int c4   = tid & 15;                   // staging: float4 index in row
    const int c8   = c4 >> 1;                    // 16B bf16 chunk (0..7)
    const int half = c4 & 1;

    for (int rep = 0; rep < REPS; ++rep) {
        asm volatile("" ::: "memory");           // no cross-rep CSE/DCE

        // --- A-fragments: global fp32 q row (i0+c) -> bf16 regs (pre-barrier) ---
        const float* qrow = q + (((size_t)b * S_LEN + i0 + c) * NH + h) * HD;
        const float4 qa0 = *(const float4*)(qrow + quad * 8);
        const float4 qa1 = *(const float4*)(qrow + quad * 8 + 4);
        const float4 qb0 = *(const float4*)(qrow + 32 + quad * 8);
        const float4 qb1 = *(const float4*)(qrow + 32 + quad * 8 + 4);

        // --- stage table: 16 rows/iter, lane = one float4 of a row ---
        #pragma unroll
        for (int it = 0; it < 16; ++it) {
            const int r = it * 16 + rrow;
            const float4 v = *(const float4*)(et + (size_t)r * EDIM + h * HD + c4 * 4);
            const ushort2 u0 = pk_bf16(v.x, v.y);
            const ushort2 u1 = pk_bf16(v.z, v.w);
            ushort4 u; u.x = u0.x; u.y = u0.y; u.z = u1.x; u.w = u1.y;
            *(ushort4*)(Tl + r * HD + ((c8 ^ (r & 7)) * 8) + half * 4) = u;
        }

        if (tid < TI) xi_s[tid] = x[b * S_LEN + i0 + tid];
        const int2 xj = *(const int2*)(x + b * S_LEN + 2 * tid);   // lane's 2 j-cols
        const int maxx = maxx_p[0];

        // pack A fragments while staging is in flight
        union { bf16x8 v; ushort2 u[4]; } a0u, a1u;
        a0u.u[0] = pk_bf16(qa0.x, qa0.y); a0u.u[1] = pk_bf16(qa0.z, qa0.w);
        a0u.u[2] = pk_bf16(qa1.x, qa1.y); a0u.u[3] = pk_bf16(qa1.z, qa1.w);
        a1u.u[0] = pk_bf16(qb0.x, qb0.y); a1u.u[1] = pk_bf16(qb0.z, qb0.w);
        a1u.u[2] = pk_bf16(qb1.x, qb1.y); a1u.u[3] = pk_bf16(qb1.z, qb1.w);

        __syncthreads();

        // --- MFMA: S[m][r] = sum_d Q[m][d] * T[r][d]; wave w covers r in w*64.. ---
        f32x4 acc[4];
        #pragma unroll
        for (int nt = 0; nt < 4; ++nt) acc[nt] = (f32x4){0.f, 0.f, 0.f, 0.f};

        #pragma unroll
        for (int nt = 0; nt < 4; ++nt) {
            const int r  = w * 64 + nt * 16 + c;     // r&7 == c&7 (16 | nt-stride)
            const int p0 = quad ^ (c & 7);
            const int p1 = (4 + quad) ^ (c & 7);
            const bf16x8 b0 = *(const bf16x8*)(Tl + r * HD + p0 * 8);
            const bf16x8 b1 = *(const bf16x8*)(Tl + r * HD + p1 * 8);
            acc[nt] = __builtin_amdgcn_mfma_f32_16x16x32_bf16(a0u.v, b0, acc[nt], 0, 0, 0);
            acc[nt] = __builtin_amdgcn_mfma_f32_16x16x32_bf16(a1u.v, b1, acc[nt], 0, 0, 0);
        }

        // C/D: lane l reg v holds D[m = quad*4 + v][n = l&15] -> Ts[r][m]
        #pragma unroll
        for (int nt = 0; nt < 4; ++nt) {
            const int r = w * 64 + nt * 16 + c;
            *(float2*)&Ts[r][quad * 4]     = float2{acc[nt][0], acc[nt][1]};
            *(float2*)&Ts[r][quad * 4 + 2] = float2{acc[nt][2], acc[nt][3]};
        }

        __syncthreads();

        // --- gather (b64 over i-pairs) + coalesced float2 stores ---
        float* obase = out + (((size_t)b * NH + h) * S_LEN + i0) * S_LEN;
        #pragma unroll
        for (int ii = 0; ii < TI; ii += 2) {
            const int r0  = (maxx + xj.x - xi_s[ii]) & 255;      // col j = 2*tid
            const int r1  = (maxx + xj.y - xi_s[ii]) & 255;      // col j = 2*tid+1
            const int r0b = (maxx + xj.x - xi_s[ii + 1]) & 255;
            const int r1b = (maxx + xj.y - xi_s[ii + 1]) & 255;
            const float2 g0 = *(const float2*)&Ts[r0][ii];
            const float2 g1 = *(const float2*)&Ts[r1][ii];
            float2 o0, o1;
            o0.x = g0.x;                                          // (ii,   j)
            o0.y = g1.x;                                          // (ii,   j+1)
            o1.x = (r0b == r0) ? g0.y : Ts[r0b][ii + 1];          // (ii+1, j)
            o1.y = (r1b == r1) ? g1.y : Ts[r1b][ii + 1];          // (ii+1, j+1)
            *(float2*)(obase + (size_t)ii * S_LEN + 2 * tid)       = o0;
            *(float2*)(obase + (size_t)(ii + 1) * S_LEN + 2 * tid) = o1;
        }

        __syncthreads();   // guard Tl/xi_s rewrite of next rep vs gather reads
    }
}

extern "C" void kernel_launch(void* const* d_in, const int* in_sizes, int n_in,
                              void* d_out, int out_size, void* d_ws, size_t ws_size,
                              hipStream_t stream) {
    const float* q    = (const float*)d_in[0];
    const float* et   = (const float*)d_in[1];
    const int*   x    = (const int*)d_in[2];
    const int*   maxx = (const int*)d_in[3];
    float*       out  = (float*)d_out;

    const int B = in_sizes[2] / S_LEN;           // 2
    dim3 grid(B * NH * (S_LEN / TI));            // 512 blocks
    relpos_kernel<<<grid, 256, 0, stream>>>(q, et, x, maxx, out);
}

// Round 4
// 67.832 us; speedup vs baseline: 1.5967x; 1.5967x over previous
//
#include <hip/hip_runtime.h>
#include <hip/hip_bf16.h>

// out[b,h,i,j] = sum_d q[b,i,h,d] * T[128 + x[b,j] - x[b,i], h*64+d]
// Round 9: scheduling polish of the round-5 structure (best, K ~= 5.5us
// measured via REPS=10: dur 108.3 = 67.8 + 9K). Harness fills ~62us are
// untouchable; kernel floor = 16.8MB out @6.3TB/s = 2.7us.
//  - staging: issue ALL 16 et float4 loads into regs, THEN cvt+ds_write.
//    Old form was a 16x {load->cvt->write} chain exposing ~16 L2 latencies
//    with only 2 waves/SIMD (VALUBusy 11%). +64 VGPR, free at this grid
//    (launch_bounds(256,2): 2 blocks/CU is all the grid provides).
//  - Ts stride 18 -> 17 (odd): gather banks 16 -> 32 reachable (~4-way ->
//    ~2-way, SQ_LDS_BANK_CONFLICT 380K/rep expected to ~halve). Scalar
//    b32 Ts writes/reads (68B rows lose 8B alignment).
//  - gather: lane owns 4 j-cols (float4 store, 8 stores/thread, was 16
//    float2) per round-6 shape; no predicated re-reads.

#define S_LEN 512
#define NH 8
#define HD 64
#define EDIM 512
#define TI 16      // i-rows per block; grid = B*NH*(S/TI) = 512 -> 2 blocks/CU
#define NR 256
#define TIP 17     // Ts row pad (floats): odd stride -> full 32-bank spread

typedef __attribute__((ext_vector_type(8))) short bf16x8;
typedef __attribute__((ext_vector_type(4))) float f32x4;

__device__ __forceinline__ ushort2 pk_bf16(float a, float b) {
    union { __hip_bfloat162 h; ushort2 u; } v;
    v.h = __float22bfloat162_rn(float2{a, b});
    return v.u;
}

__global__ __launch_bounds__(256, 2) void relpos_kernel(
    const float* __restrict__ q,     // [B, S, H, D]
    const float* __restrict__ et,    // [257, E]
    const int*   __restrict__ x,     // [B, S]
    const int*   __restrict__ maxx_p,
    float*       __restrict__ out)   // [B, H, S, S]
{
    const int tid = threadIdx.x;
    const int per = S_LEN / TI;                  // 32
    const int b   = blockIdx.x / (NH * per);
    const int h   = (blockIdx.x / per) % NH;
    const int i0  = (blockIdx.x % per) * TI;

    __shared__ unsigned short Tl[NR * HD];       // 32 KB swizzled bf16 table slice
    __shared__ float          Ts[NR][TIP];       // 17.4 KB scores, [r][i] layout
    __shared__ int            xi_s[TI];

    const int w    = tid >> 6;
    const int l    = tid & 63;
    const int quad = l >> 4;
    const int c    = l & 15;
    const int rrow = tid >> 4;                   // staging: row within iter group
    const int c4   = tid & 15;                   // staging: float4 index in row
    const int c8   = c4 >> 1;                    // 16B bf16 chunk (0..7)
    const int half = c4 & 1;

    // --- stage loads: ALL 16 et float4 issued before any consumption ---
    float4 tv[16];
    #pragma unroll
    for (int it = 0; it < 16; ++it) {
        const int r = it * 16 + rrow;
        tv[it] = *(const float4*)(et + (size_t)r * EDIM + h * HD + c4 * 4);
    }

    // --- A-fragment loads: global fp32 q row (i0+c) ---
    const float* qrow = q + (((size_t)b * S_LEN + i0 + c) * NH + h) * HD;
    const float4 qa0 = *(const float4*)(qrow + quad * 8);
    const float4 qa1 = *(const float4*)(qrow + quad * 8 + 4);
    const float4 qb0 = *(const float4*)(qrow + 32 + quad * 8);
    const float4 qb1 = *(const float4*)(qrow + 32 + quad * 8 + 4);

    if (tid < TI) xi_s[tid] = x[b * S_LEN + i0 + tid];
    const int4 xj4 = *(const int4*)(x + b * S_LEN + 4 * (tid & 127)); // 4 j-cols
    const int maxx = maxx_p[0];

    // --- cvt + ds_write, consuming tv[] in issue order (vmcnt pipelined) ---
    #pragma unroll
    for (int it = 0; it < 16; ++it) {
        const int r = it * 16 + rrow;
        const ushort2 u0 = pk_bf16(tv[it].x, tv[it].y);
        const ushort2 u1 = pk_bf16(tv[it].z, tv[it].w);
        ushort4 u; u.x = u0.x; u.y = u0.y; u.z = u1.x; u.w = u1.y;
        *(ushort4*)(Tl + r * HD + ((c8 ^ (r & 7)) * 8) + half * 4) = u;
    }

    // pack A fragments (waits only on q loads)
    union { bf16x8 v; ushort2 u[4]; } a0u, a1u;
    a0u.u[0] = pk_bf16(qa0.x, qa0.y); a0u.u[1] = pk_bf16(qa0.z, qa0.w);
    a0u.u[2] = pk_bf16(qa1.x, qa1.y); a0u.u[3] = pk_bf16(qa1.z, qa1.w);
    a1u.u[0] = pk_bf16(qb0.x, qb0.y); a1u.u[1] = pk_bf16(qb0.z, qb0.w);
    a1u.u[2] = pk_bf16(qb1.x, qb1.y); a1u.u[3] = pk_bf16(qb1.z, qb1.w);

    __syncthreads();

    // --- MFMA: S[m][r] = sum_d Q[m][d] * T[r][d]; wave w covers r in w*64.. ---
    f32x4 acc[4];
    #pragma unroll
    for (int nt = 0; nt < 4; ++nt) acc[nt] = (f32x4){0.f, 0.f, 0.f, 0.f};

    #pragma unroll
    for (int nt = 0; nt < 4; ++nt) {
        const int r  = w * 64 + nt * 16 + c;     // r&7 == c&7 (16 | nt-stride)
        const int p0 = quad ^ (c & 7);
        const int p1 = (4 + quad) ^ (c & 7);
        const bf16x8 b0 = *(const bf16x8*)(Tl + r * HD + p0 * 8);
        const bf16x8 b1 = *(const bf16x8*)(Tl + r * HD + p1 * 8);
        acc[nt] = __builtin_amdgcn_mfma_f32_16x16x32_bf16(a0u.v, b0, acc[nt], 0, 0, 0);
        acc[nt] = __builtin_amdgcn_mfma_f32_16x16x32_bf16(a1u.v, b1, acc[nt], 0, 0, 0);
    }

    // C/D: lane l reg v holds D[m = quad*4 + v][n = c] -> Ts[r][m], scalar b32
    #pragma unroll
    for (int nt = 0; nt < 4; ++nt) {
        const int r = w * 64 + nt * 16 + c;
        Ts[r][quad * 4 + 0] = acc[nt][0];
        Ts[r][quad * 4 + 1] = acc[nt][1];
        Ts[r][quad * 4 + 2] = acc[nt][2];
        Ts[r][quad * 4 + 3] = acc[nt][3];
    }

    __syncthreads();

    // --- gather: lane owns row {ii + (tid>>7)} x 4 j-cols, float4 stores ---
    float* obase = out + (((size_t)b * NH + h) * S_LEN + i0) * S_LEN;
    const int jg     = (tid & 127) * 4;
    const int rowsel = tid >> 7;
    #pragma unroll
    for (int ii = 0; ii < TI; ii += 2) {
        const int row = ii + rowsel;
        const int xi  = xi_s[row];
        float4 o;
        o.x = Ts[(maxx + xj4.x - xi) & 255][row];
        o.y = Ts[(maxx + xj4.y - xi) & 255][row];
        o.z = Ts[(maxx + xj4.z - xi) & 255][row];
        o.w = Ts[(maxx + xj4.w - xi) & 255][row];
        *(float4*)(obase + (size_t)row * S_LEN + jg) = o;
    }
}

extern "C" void kernel_launch(void* const* d_in, const int* in_sizes, int n_in,
                              void* d_out, int out_size, void* d_ws, size_t ws_size,
                              hipStream_t stream) {
    const float* q    = (const float*)d_in[0];
    const float* et   = (const float*)d_in[1];
    const int*   x    = (const int*)d_in[2];
    const int*   maxx = (const int*)d_in[3];
    float*       out  = (float*)d_out;

    const int B = in_sizes[2] / S_LEN;           // 2
    dim3 grid(B * NH * (S_LEN / TI));            // 512 blocks
    relpos_kernel<<<grid, 256, 0, stream>>>(q, et, x, maxx, out);
}